// Round 1
// baseline (2541.842 us; speedup 1.0000x reference)
//
#include <hip/hip_runtime.h>
#include <cmath>

#define B_  4
#define C_  512
#define N_  16384
#define H_  8
#define D_  64
#define C3_ 1536
#define EPS 1e-6f

__device__ __forceinline__ float phi_f(float x) {
    // elu(x)+1
    return x > 0.f ? x + 1.f : __expf(x);
}

// ---------------------------------------------------------------------------
// Kernel A: fused KV GEMM + S = phi(K)^T V rank-reduction + k_sum.
// Grid: (h=8, s=32, b=4), block 256. Each WG owns 8 n-tiles of 64 tokens,
// keeps S partial [64x64] in registers across tiles, atomicAdd once at end.
// ---------------------------------------------------------------------------
__global__ __launch_bounds__(256) void kernelA(
        const float* __restrict__ x, const float* __restrict__ Wqkv,
        const float* __restrict__ bqkv, float* __restrict__ S_g,
        float* __restrict__ ksum_g) {
    const int h = blockIdx.x;
    const int s = blockIdx.y;
    const int b = blockIdx.z;
    const int tid = threadIdx.x;
    const int tn = tid & 15;   // n-group for kv GEMM
    const int tj = tid >> 4;   // j-group 0..15 (j = tj*8.. : tj<8 -> k cols, else v cols)
    const int td = tid & 15;   // d-group for S GEMM
    const int te = tid >> 4;   // e-group for S GEMM

    __shared__ float As[16][64];      // x chunk  [k][n]
    __shared__ float Bs[16][128];     // W chunk  [k][j] (64 k-cols | 64 v-cols)
    __shared__ float kphi_s[64][64];  // [n][d]
    __shared__ float v_s[64][64];     // [n][e]

    float acc2[4][4];
    #pragma unroll
    for (int i = 0; i < 4; i++)
        #pragma unroll
        for (int j = 0; j < 4; j++) acc2[i][j] = 0.f;
    float ksum_r = 0.f;

    float bias_j[8];
    #pragma unroll
    for (int jj = 0; jj < 8; jj++) {
        int j = tj * 8 + jj;
        int col = (j < 64) ? (512 + h * 64 + j) : (1024 + h * 64 + (j - 64));
        bias_j[jj] = bqkv[col];
    }

    for (int it = 0; it < 8; ++it) {
        const int n0 = (s * 8 + it) * 64;

        float acc[4][8];
        #pragma unroll
        for (int i = 0; i < 4; i++)
            #pragma unroll
            for (int jj = 0; jj < 8; jj++) acc[i][jj] = 0.f;

        for (int kc = 0; kc < 32; ++kc) {
            const int c0 = kc * 16;
            __syncthreads();
            {   // stage x chunk: rows c0..c0+15, 64 tokens
                int r = tid >> 4, n4 = (tid & 15) * 4;
                const float* src = x + ((size_t)b * C_ + (c0 + r)) * (size_t)N_ + n0 + n4;
                *(float4*)&As[r][n4] = *(const float4*)src;
            }
            #pragma unroll
            for (int part = 0; part < 2; ++part) {  // stage W chunk (k|v cols of head h)
                int idx = tid + part * 256;
                int r = idx >> 5;
                int j4 = (idx & 31) * 4;
                int col = (j4 < 64) ? (512 + h * 64 + j4) : (1024 + h * 64 + (j4 - 64));
                const float* src = Wqkv + (size_t)(c0 + r) * C3_ + col;
                *(float4*)&Bs[r][j4] = *(const float4*)src;
            }
            __syncthreads();
            #pragma unroll
            for (int k = 0; k < 16; ++k) {
                float a[4], bb[8];
                *(float4*)a       = *(const float4*)&As[k][tn * 4];
                *(float4*)&bb[0]  = *(const float4*)&Bs[k][tj * 8];
                *(float4*)&bb[4]  = *(const float4*)&Bs[k][tj * 8 + 4];
                #pragma unroll
                for (int i = 0; i < 4; i++)
                    #pragma unroll
                    for (int jj = 0; jj < 8; jj++)
                        acc[i][jj] = fmaf(a[i], bb[jj], acc[i][jj]);
            }
        }
        __syncthreads();
        // write phi(k) / v tiles to LDS
        if (tj < 8) {
            #pragma unroll
            for (int i = 0; i < 4; i++) {
                int n = tn * 4 + i;
                float tmp[8];
                #pragma unroll
                for (int jj = 0; jj < 8; jj++) tmp[jj] = phi_f(acc[i][jj] + bias_j[jj]);
                *(float4*)&kphi_s[n][tj * 8]     = *(float4*)&tmp[0];
                *(float4*)&kphi_s[n][tj * 8 + 4] = *(float4*)&tmp[4];
            }
        } else {
            #pragma unroll
            for (int i = 0; i < 4; i++) {
                int n = tn * 4 + i;
                float tmp[8];
                #pragma unroll
                for (int jj = 0; jj < 8; jj++) tmp[jj] = acc[i][jj] + bias_j[jj];
                *(float4*)&v_s[n][(tj - 8) * 8]     = *(float4*)&tmp[0];
                *(float4*)&v_s[n][(tj - 8) * 8 + 4] = *(float4*)&tmp[4];
            }
        }
        __syncthreads();
        // S rank-update: acc2[dd][ee] += sum_n kphi[n][d] * v[n][e]
        #pragma unroll 4
        for (int n = 0; n < 64; ++n) {
            float a[4], bb[4];
            *(float4*)a  = *(const float4*)&kphi_s[n][td * 4];
            *(float4*)bb = *(const float4*)&v_s[n][te * 4];
            #pragma unroll
            for (int dd = 0; dd < 4; dd++)
                #pragma unroll
                for (int ee = 0; ee < 4; ee++)
                    acc2[dd][ee] = fmaf(a[dd], bb[ee], acc2[dd][ee]);
        }
        if (tid < 64) {
            float sum = 0.f;
            #pragma unroll 8
            for (int n = 0; n < 64; ++n) sum += kphi_s[n][tid];
            ksum_r += sum;
        }
    }

    const int bh = b * H_ + h;
    #pragma unroll
    for (int dd = 0; dd < 4; dd++)
        #pragma unroll
        for (int ee = 0; ee < 4; ee++)
            atomicAdd(&S_g[((size_t)bh * 64 + td * 4 + dd) * 64 + te * 4 + ee], acc2[dd][ee]);
    if (tid < 64) atomicAdd(&ksum_g[bh * 64 + tid], ksum_r);
}

// ---------------------------------------------------------------------------
// Kernel B: fused Q GEMM + phi + num/den + in-LDS attn + proj GEMM + store.
// Grid: (N/16, B), block 256. 16-token tile per WG; QA[512][16] holds phi(q)
// then is overwritten head-by-head with attn, then feeds the proj GEMM.
// ---------------------------------------------------------------------------
__global__ __launch_bounds__(256) void kernelB(
        const float* __restrict__ x, const float* __restrict__ Wqkv,
        const float* __restrict__ bqkv, const float* __restrict__ Wproj,
        const float* __restrict__ bproj, const float* __restrict__ S_g,
        const float* __restrict__ ksum_g, float* __restrict__ out) {
    const int nt = blockIdx.x;
    const int b  = blockIdx.y;
    const int n0 = nt * 16;
    const int tid = threadIdx.x;
    const int tn = tid & 3;    // n-quad (n = tn*4+i)
    const int tj = tid >> 2;   // 0..63 column group

    __shared__ float QA[512][16];    // phi(q) then attn, [c'][n]  (32 KB)
    __shared__ float As[16][16];     // x chunk (1 KB)
    __shared__ float Bs2[16][256];   // W chunk (16 KB)
    __shared__ float SB[16][64];     // S chunk (4 KB)
    __shared__ float ksumL[512];     // (2 KB)
    __shared__ float denL[16];

    ksumL[tid]       = ksum_g[(size_t)b * 512 + tid];
    ksumL[tid + 256] = ksum_g[(size_t)b * 512 + tid + 256];

    // ---- Phase 1: q GEMM (all heads), two 256-col halves ----
    for (int half = 0; half < 2; ++half) {
        float acc[4][4];
        #pragma unroll
        for (int i = 0; i < 4; i++)
            #pragma unroll
            for (int j = 0; j < 4; j++) acc[i][j] = 0.f;

        for (int kc = 0; kc < 32; ++kc) {
            const int c0 = kc * 16;
            __syncthreads();
            {
                int r = tid >> 4, n = tid & 15;
                As[r][n] = x[((size_t)b * C_ + c0 + r) * (size_t)N_ + n0 + n];
            }
            {
                int r = tid >> 4;
                int j0 = (tid & 15) * 16;
                const float* src = Wqkv + (size_t)(c0 + r) * C3_ + half * 256 + j0;
                float4* dst = (float4*)&Bs2[r][j0];
                #pragma unroll
                for (int q4 = 0; q4 < 4; q4++) dst[q4] = ((const float4*)src)[q4];
            }
            __syncthreads();
            #pragma unroll
            for (int k = 0; k < 16; ++k) {
                float a[4], bb[4];
                *(float4*)a  = *(const float4*)&As[k][tn * 4];
                *(float4*)bb = *(const float4*)&Bs2[k][tj * 4];
                #pragma unroll
                for (int i = 0; i < 4; i++)
                    #pragma unroll
                    for (int jj = 0; jj < 4; jj++)
                        acc[i][jj] = fmaf(a[i], bb[jj], acc[i][jj]);
            }
        }
        // write phi(q) rows for this half
        #pragma unroll
        for (int jj = 0; jj < 4; jj++) {
            int c = half * 256 + tj * 4 + jj;
            float bq = bqkv[c];
            float tmp[4];
            #pragma unroll
            for (int i = 0; i < 4; i++) tmp[i] = phi_f(acc[i][jj] + bq);
            *(float4*)&QA[c][tn * 4] = *(float4*)tmp;
        }
    }
    __syncthreads();

    // ---- Phase 2: per-head den, num = phi(q) @ S, attn overwrites QA rows ----
    for (int h = 0; h < H_; ++h) {
        if (tid < 16) {
            float d = 0.f;
            #pragma unroll 8
            for (int dd = 0; dd < 64; ++dd)
                d = fmaf(QA[h * 64 + dd][tid], ksumL[h * 64 + dd], d);
            denL[tid] = d + EPS;
        }
        float acc4[4] = {0.f, 0.f, 0.f, 0.f};
        for (int dc = 0; dc < 4; ++dc) {
            __syncthreads();
            {
                int r = tid >> 4, e4 = (tid & 15) * 4;
                *(float4*)&SB[r][e4] =
                    *(const float4*)&S_g[(((size_t)(b * H_ + h)) * 64 + dc * 16 + r) * 64 + e4];
            }
            __syncthreads();
            #pragma unroll
            for (int k = 0; k < 16; ++k) {
                float a[4];
                *(float4*)a = *(const float4*)&QA[h * 64 + dc * 16 + k][tn * 4];
                float bb = SB[k][tj];
                #pragma unroll
                for (int i = 0; i < 4; i++) acc4[i] = fmaf(a[i], bb, acc4[i]);
            }
        }
        __syncthreads();   // all num reads of QA rows done; denL visible
        {
            float tmp[4];
            #pragma unroll
            for (int i = 0; i < 4; i++) tmp[i] = acc4[i] / denL[tn * 4 + i];
            *(float4*)&QA[h * 64 + tj][tn * 4] = *(float4*)tmp;
        }
        __syncthreads();   // attn written (and denL reads done) before next head
    }

    // ---- Phase 3: proj GEMM out = attn @ Wproj + bproj, transposed store ----
    for (int half = 0; half < 2; ++half) {
        float acc[4][4];
        #pragma unroll
        for (int i = 0; i < 4; i++)
            #pragma unroll
            for (int j = 0; j < 4; j++) acc[i][j] = 0.f;

        for (int kc = 0; kc < 32; ++kc) {
            __syncthreads();
            {
                int r = tid >> 4;
                int j0 = (tid & 15) * 16;
                const float* src = Wproj + (size_t)(kc * 16 + r) * C_ + half * 256 + j0;
                float4* dst = (float4*)&Bs2[r][j0];
                #pragma unroll
                for (int q4 = 0; q4 < 4; q4++) dst[q4] = ((const float4*)src)[q4];
            }
            __syncthreads();
            #pragma unroll
            for (int k = 0; k < 16; ++k) {
                float a[4], bb[4];
                *(float4*)a  = *(const float4*)&QA[kc * 16 + k][tn * 4];
                *(float4*)bb = *(const float4*)&Bs2[k][tj * 4];
                #pragma unroll
                for (int i = 0; i < 4; i++)
                    #pragma unroll
                    for (int jj = 0; jj < 4; jj++)
                        acc[i][jj] = fmaf(a[i], bb[jj], acc[i][jj]);
            }
        }
        #pragma unroll
        for (int jj = 0; jj < 4; jj++) {
            int c = half * 256 + tj * 4 + jj;
            float bp = bproj[c];
            float tmp[4];
            #pragma unroll
            for (int i = 0; i < 4; i++) tmp[i] = acc[i][jj] + bp;
            *(float4*)&out[((size_t)b * C_ + c) * (size_t)N_ + n0 + tn * 4] = *(float4*)tmp;
        }
    }
}

extern "C" void kernel_launch(void* const* d_in, const int* in_sizes, int n_in,
                              void* d_out, int out_size, void* d_ws, size_t ws_size,
                              hipStream_t stream) {
    const float* x     = (const float*)d_in[0];
    const float* Wqkv  = (const float*)d_in[1];
    const float* bqkv  = (const float*)d_in[2];
    const float* Wproj = (const float*)d_in[3];
    const float* bproj = (const float*)d_in[4];
    float* out = (float*)d_out;

    float* S_g    = (float*)d_ws;                       // [B,H,64,64]
    float* ksum_g = S_g + (size_t)B_ * H_ * D_ * D_;    // [B,H,64]

    hipMemsetAsync(d_ws, 0,
                   ((size_t)B_ * H_ * D_ * D_ + (size_t)B_ * H_ * D_) * sizeof(float),
                   stream);
    kernelA<<<dim3(H_, 32, B_), 256, 0, stream>>>(x, Wqkv, bqkv, S_g, ksum_g);
    kernelB<<<dim3(N_ / 16, B_), 256, 0, stream>>>(x, Wqkv, bqkv, Wproj, bproj,
                                                   S_g, ksum_g, out);
}

// Round 2
// 534.330 us; speedup vs baseline: 4.7571x; 4.7571x over previous
//
#include <hip/hip_runtime.h>
#include <cmath>

#define B_  4
#define C_  512
#define N_  16384
#define H_  8
#define D_  64
#define C3_ 1536
#define EPS 1e-6f

#define PADA 72    // bf16 tile leading pad: 144B stride -> balanced bank groups, 16B aligned
#define PADT 136   // [j][n] transposed kv tile pad
#define PADO 132   // f32 out-transpose pad

typedef __attribute__((ext_vector_type(8))) short bf16x8;
typedef __attribute__((ext_vector_type(4))) float f32x4;

__device__ __forceinline__ ushort f2bf(float f) {
    union { float f; unsigned u; } c{f};
    unsigned r = (c.u + 0x7FFF + ((c.u >> 16) & 1)) >> 16;  // RNE
    return (ushort)r;
}
__device__ __forceinline__ float bf2f(ushort b) {
    union { unsigned u; float f; } c{(unsigned)b << 16};
    return c.f;
}
__device__ __forceinline__ float phi_f(float x) { return x > 0.f ? x + 1.f : __expf(x); }

// ---------------------------------------------------------------------------
// Generic transpose+cast: src f32 [R][Cc] -> dst bf16 [Cc][R].  Tiles 64x64.
// grid (Cc/64, R/64, batch)
// ---------------------------------------------------------------------------
__global__ __launch_bounds__(256) void k_transpose(
        const float* __restrict__ src, ushort* __restrict__ dst,
        int R, int Cc, long sStride, long dStride) {
    __shared__ ushort T[64][72];
    const long sb = (long)blockIdx.z * sStride;
    const long db = (long)blockIdx.z * dStride;
    const int c0 = blockIdx.x * 64, r0 = blockIdx.y * 64;
    const int t = threadIdx.x;
    const int ct = t & 15, rt = t >> 4;   // 16 col-tiles x 16 row-tiles of 4x4
    float4 v[4];
    #pragma unroll
    for (int k = 0; k < 4; ++k)
        v[k] = *(const float4*)(src + sb + (long)(r0 + rt * 4 + k) * Cc + c0 + ct * 4);
    #pragma unroll
    for (int j = 0; j < 4; ++j) {
        ushort pk[4];
        #pragma unroll
        for (int k = 0; k < 4; ++k) pk[k] = f2bf(((const float*)&v[k])[j]);
        *(uint2*)&T[ct * 4 + j][rt * 4] = *(uint2*)pk;   // ds_write_b64
    }
    __syncthreads();
    const int c = t >> 2, rq = (t & 3) * 16;
    ushort* d = dst + db + (long)(c0 + c) * R + r0 + rq;
    *(int4*)(d)     = *(const int4*)&T[c][rq];
    *(int4*)(d + 8) = *(const int4*)&T[c][rq + 8];
}

// ---------------------------------------------------------------------------
// Fused kv GEMM (bf16 MFMA) + phi + S = phi(K)^T V + k_sum.
// grid (s=16, h=8, b=4), 256 thr / 4 waves. Each WG: 8 subtiles of 128 tokens.
// ---------------------------------------------------------------------------
__global__ __launch_bounds__(256) void k_kv_s(
        const ushort* __restrict__ xt, const ushort* __restrict__ Wqt,
        const float* __restrict__ bqkv, float* __restrict__ S_g,
        float* __restrict__ ksum_g) {
    const int s = blockIdx.x, h = blockIdx.y, b = blockIdx.z;
    const int tid = threadIdx.x;
    const int w = tid >> 6, ln = tid & 63, lr = ln & 15, lq = ln >> 4;
    const int bh = b * H_ + h;

    __shared__ __align__(16) char smem[128 * PADA * 2 * 2];  // 36864B; Ax|Bw alias kvT
    ushort (*Ax)[PADA]  = (ushort(*)[PADA])smem;
    ushort (*Bw)[PADA]  = (ushort(*)[PADA])(smem + 128 * PADA * 2);
    ushort (*kvT)[PADT] = (ushort(*)[PADT])smem;  // rows 0..63 kphi^T[d][n], 64..127 v^T[e][n]
    __shared__ float biasL[128];
    __shared__ float ksRed[4][64];

    if (tid < 128) {
        int col = tid < 64 ? (512 + h * 64 + tid) : (1024 + h * 64 + (tid - 64));
        biasL[tid] = bqkv[col];
    }

    const f32x4 FZ = {0.f, 0.f, 0.f, 0.f};
    f32x4 Sacc[4] = {FZ, FZ, FZ, FZ};
    float ksp = 0.f;

    for (int it = 0; it < 8; ++it) {
        const int n0 = (s * 8 + it) * 128;
        f32x4 acc[2][8];
        #pragma unroll
        for (int mi = 0; mi < 2; mi++)
            #pragma unroll
            for (int ji = 0; ji < 8; ji++) acc[mi][ji] = FZ;

        for (int kc = 0; kc < 8; ++kc) {
            const int c0 = kc * 64;
            __syncthreads();
            {
                int row = tid >> 1, co = (tid & 1) * 32;
                const int4* srca = (const int4*)(xt + ((long)(b * N_ + n0 + row)) * C_ + c0 + co);
                int4* dsta = (int4*)&Ax[row][co];
                dsta[0] = srca[0]; dsta[1] = srca[1]; dsta[2] = srca[2]; dsta[3] = srca[3];
                int j = row;
                int wr = j < 64 ? (512 + h * 64 + j) : (1024 + h * 64 + (j - 64));
                const int4* srcb = (const int4*)(Wqt + (long)wr * C_ + c0 + co);
                int4* dstb = (int4*)&Bw[j][co];
                dstb[0] = srcb[0]; dstb[1] = srcb[1]; dstb[2] = srcb[2]; dstb[3] = srcb[3];
            }
            __syncthreads();
            #pragma unroll
            for (int ks = 0; ks < 2; ++ks) {
                bf16x8 a[2], bb[8];
                #pragma unroll
                for (int mi = 0; mi < 2; mi++)
                    a[mi] = *(const bf16x8*)&Ax[w * 32 + mi * 16 + lr][ks * 32 + lq * 8];
                #pragma unroll
                for (int ji = 0; ji < 8; ji++)
                    bb[ji] = *(const bf16x8*)&Bw[ji * 16 + lr][ks * 32 + lq * 8];
                #pragma unroll
                for (int mi = 0; mi < 2; mi++)
                    #pragma unroll
                    for (int ji = 0; ji < 8; ji++)
                        acc[mi][ji] = __builtin_amdgcn_mfma_f32_16x16x32_bf16(
                            a[mi], bb[ji], acc[mi][ji], 0, 0, 0);
            }
        }
        __syncthreads();
        // epilogue: bias + phi(k) -> kvT (overwrites Ax/Bw)
        #pragma unroll
        for (int mi = 0; mi < 2; mi++) {
            int nl = w * 32 + mi * 16 + lq * 4;
            #pragma unroll
            for (int ji = 0; ji < 8; ji++) {
                int j = ji * 16 + lr;
                float bs = biasL[j];
                ushort pk[4];
                #pragma unroll
                for (int r = 0; r < 4; r++) {
                    float vv = acc[mi][ji][r] + bs;
                    if (j < 64) vv = phi_f(vv);
                    pk[r] = f2bf(vv);
                }
                *(uint2*)&kvT[j][nl] = *(uint2*)pk;
            }
        }
        __syncthreads();
        // S rank-update: wave w owns d-strip w*16..w*16+15
        #pragma unroll
        for (int ks = 0; ks < 4; ++ks) {
            bf16x8 af = *(const bf16x8*)&kvT[w * 16 + lr][ks * 32 + lq * 8];
            #pragma unroll
            for (int e = 0; e < 4; e++) {
                bf16x8 bv = *(const bf16x8*)&kvT[64 + e * 16 + lr][ks * 32 + lq * 8];
                Sacc[e] = __builtin_amdgcn_mfma_f32_16x16x32_bf16(af, bv, Sacc[e], 0, 0, 0);
            }
        }
        // k_sum partial
        {
            int d = tid & 63, q = tid >> 6;
            float sum = 0.f;
            #pragma unroll
            for (int m = 0; m < 4; m++) {
                bf16x8 u = *(const bf16x8*)&kvT[d][q * 32 + m * 8];
                #pragma unroll
                for (int j = 0; j < 8; j++) sum += bf2f((ushort)u[j]);
            }
            ksp += sum;
        }
    }
    #pragma unroll
    for (int e = 0; e < 4; e++)
        #pragma unroll
        for (int r = 0; r < 4; r++)
            atomicAdd(&S_g[((long)bh * 64 + w * 16 + lq * 4 + r) * 64 + e * 16 + lr],
                      Sacc[e][r]);
    ksRed[tid >> 6][tid & 63] = ksp;
    __syncthreads();
    if (tid < 64)
        atomicAdd(&ksum_g[bh * 64 + tid],
                  ksRed[0][tid] + ksRed[1][tid] + ksRed[2][tid] + ksRed[3][tid]);
}

// ---------------------------------------------------------------------------
// S finalize: SbT[bh][160][64] bf16: rows 0..63 = S^T hi, row 64 = ksum hi,
// 65..79 = 0; rows 80..159 = lo residuals (hi+lo double-bf16).
// ---------------------------------------------------------------------------
__global__ void k_sfin(const float* __restrict__ S_g, const float* __restrict__ ksum_g,
                       ushort* __restrict__ SbT) {
    int bh = blockIdx.x, t = threadIdx.x;
    for (int i = t; i < 5120; i += 256) {
        int e = i >> 6, d = i & 63;
        float v = (e < 64) ? S_g[(long)bh * 4096 + d * 64 + e]
                           : (e == 64 ? ksum_g[bh * 64 + d] : 0.f);
        ushort hi = f2bf(v);
        ushort lo = f2bf(v - bf2f(hi));
        SbT[(long)bh * 10240 + i] = hi;
        SbT[(long)bh * 10240 + 5120 + i] = lo;
    }
}

// ---------------------------------------------------------------------------
// Fused q GEMM + phi + num/den (MFMA, ksum as e-col 64, hi+lo S) + attn store.
// grid (ntile=128, h=8, b=4), 256 thr.
// ---------------------------------------------------------------------------
__global__ __launch_bounds__(256) void k_q_attn(
        const ushort* __restrict__ xt, const ushort* __restrict__ Wqt,
        const float* __restrict__ bqkv, const ushort* __restrict__ SbT,
        ushort* __restrict__ attn) {
    const int nt = blockIdx.x, h = blockIdx.y, b = blockIdx.z;
    const int n0 = nt * 128;
    const int tid = threadIdx.x;
    const int w = tid >> 6, ln = tid & 63, lr = ln & 15, lq = ln >> 4;
    const int bh = b * H_ + h;

    __shared__ __align__(16) ushort Ax[128][PADA];  // xt tile -> phi(q) -> attn
    __shared__ __align__(16) ushort Bq[64][PADA];
    __shared__ __align__(16) ushort Sb[160][PADA];
    __shared__ float denL[128];

    // stage S (hi+lo)
    #pragma unroll
    for (int p = 0; p < 5; ++p) {
        int r = p * 32 + (tid >> 3);
        *(int4*)&Sb[r][(tid & 7) * 8] =
            *(const int4*)(SbT + (long)bh * 10240 + r * 64 + (tid & 7) * 8);
    }

    const f32x4 FZ = {0.f, 0.f, 0.f, 0.f};
    f32x4 accq[2][4];
    #pragma unroll
    for (int mi = 0; mi < 2; mi++)
        #pragma unroll
        for (int ji = 0; ji < 4; ji++) accq[mi][ji] = FZ;

    for (int kc = 0; kc < 8; ++kc) {
        const int c0 = kc * 64;
        __syncthreads();
        {
            int row = tid >> 1, co = (tid & 1) * 32;
            const int4* srca = (const int4*)(xt + ((long)(b * N_ + n0 + row)) * C_ + c0 + co);
            int4* dsta = (int4*)&Ax[row][co];
            dsta[0] = srca[0]; dsta[1] = srca[1]; dsta[2] = srca[2]; dsta[3] = srca[3];
            if (tid < 128) {
                int j = tid >> 1;
                const int4* srcb = (const int4*)(Wqt + (long)(h * 64 + j) * C_ + c0 + co);
                int4* dstb = (int4*)&Bq[j][co];
                dstb[0] = srcb[0]; dstb[1] = srcb[1]; dstb[2] = srcb[2]; dstb[3] = srcb[3];
            }
        }
        __syncthreads();
        #pragma unroll
        for (int ks = 0; ks < 2; ++ks) {
            bf16x8 a[2], bb[4];
            #pragma unroll
            for (int mi = 0; mi < 2; mi++)
                a[mi] = *(const bf16x8*)&Ax[w * 32 + mi * 16 + lr][ks * 32 + lq * 8];
            #pragma unroll
            for (int ji = 0; ji < 4; ji++)
                bb[ji] = *(const bf16x8*)&Bq[ji * 16 + lr][ks * 32 + lq * 8];
            #pragma unroll
            for (int mi = 0; mi < 2; mi++)
                #pragma unroll
                for (int ji = 0; ji < 4; ji++)
                    accq[mi][ji] = __builtin_amdgcn_mfma_f32_16x16x32_bf16(
                        a[mi], bb[ji], accq[mi][ji], 0, 0, 0);
        }
    }
    __syncthreads();
    // phi(q) -> Ax[n][d] (wave-private rows)
    #pragma unroll
    for (int mi = 0; mi < 2; mi++) {
        int nl = w * 32 + mi * 16 + lq * 4;
        #pragma unroll
        for (int ji = 0; ji < 4; ji++) {
            int d = ji * 16 + lr;
            float bs = bqkv[h * 64 + d];
            #pragma unroll
            for (int r = 0; r < 4; r++)
                Ax[nl + r][d] = f2bf(phi_f(accq[mi][ji][r] + bs));
        }
    }
    __syncthreads();
    // num (+den col 64) MFMA, hi+lo
    f32x4 accn[2][5];
    #pragma unroll
    for (int mi = 0; mi < 2; mi++)
        #pragma unroll
        for (int ei = 0; ei < 5; ei++) accn[mi][ei] = FZ;
    #pragma unroll
    for (int ks = 0; ks < 2; ++ks) {
        bf16x8 a[2];
        #pragma unroll
        for (int mi = 0; mi < 2; mi++)
            a[mi] = *(const bf16x8*)&Ax[w * 32 + mi * 16 + lr][ks * 32 + lq * 8];
        #pragma unroll
        for (int ei = 0; ei < 5; ei++) {
            bf16x8 bhi = *(const bf16x8*)&Sb[ei * 16 + lr][ks * 32 + lq * 8];
            bf16x8 blo = *(const bf16x8*)&Sb[80 + ei * 16 + lr][ks * 32 + lq * 8];
            #pragma unroll
            for (int mi = 0; mi < 2; mi++) {
                accn[mi][ei] = __builtin_amdgcn_mfma_f32_16x16x32_bf16(
                    a[mi], bhi, accn[mi][ei], 0, 0, 0);
                accn[mi][ei] = __builtin_amdgcn_mfma_f32_16x16x32_bf16(
                    a[mi], blo, accn[mi][ei], 0, 0, 0);
            }
        }
    }
    if (lr == 0) {
        #pragma unroll
        for (int mi = 0; mi < 2; mi++)
            #pragma unroll
            for (int r = 0; r < 4; r++)
                denL[w * 32 + mi * 16 + lq * 4 + r] = accn[mi][4][r] + EPS;
    }
    __syncthreads();
    // attn = num/den -> Ax
    #pragma unroll
    for (int mi = 0; mi < 2; mi++) {
        int nl = w * 32 + mi * 16 + lq * 4;
        #pragma unroll
        for (int ji = 0; ji < 4; ji++) {
            int e = ji * 16 + lr;
            #pragma unroll
            for (int r = 0; r < 4; r++)
                Ax[nl + r][e] = f2bf(accn[mi][ji][r] / denL[nl + r]);
        }
    }
    __syncthreads();
    // coalesced store: attn ws [b][n][h*64 .. h*64+64)
    {
        int row = tid >> 1, co = (tid & 1) * 32;
        const int4* sp = (const int4*)&Ax[row][co];
        int4* dp = (int4*)(attn + ((long)(b * N_ + n0 + row)) * C_ + h * 64 + co);
        dp[0] = sp[0]; dp[1] = sp[1]; dp[2] = sp[2]; dp[3] = sp[3];
    }
}

// ---------------------------------------------------------------------------
// Proj GEMM: out[b][cout][n] = attn[n'][c] @ Wp_t[cout][c] + bias.
// grid (nt=512, jt=4), 128x128 tile, LDS-transposed coalesced f32 store.
// ---------------------------------------------------------------------------
__global__ __launch_bounds__(256) void k_proj(
        const ushort* __restrict__ attn, const ushort* __restrict__ Wpt,
        const float* __restrict__ bproj, float* __restrict__ out) {
    const int nt = blockIdx.x, jt = blockIdx.y;
    const int tid = threadIdx.x;
    const int w = tid >> 6, ln = tid & 63, lr = ln & 15, lq = ln >> 4;
    const int b = nt >> 7;
    const int nloc = (nt & 127) * 128;

    __shared__ __align__(16) char smem[128 * PADA * 2 * 2];
    ushort (*Aa)[PADA] = (ushort(*)[PADA])smem;
    ushort (*Bw)[PADA] = (ushort(*)[PADA])(smem + 128 * PADA * 2);
    float (*outT)[PADO] = (float(*)[PADO])smem;   // 64x132x4 = 33792 <= 36864

    const f32x4 FZ = {0.f, 0.f, 0.f, 0.f};
    f32x4 acc[2][8];
    #pragma unroll
    for (int mi = 0; mi < 2; mi++)
        #pragma unroll
        for (int ji = 0; ji < 8; ji++) acc[mi][ji] = FZ;

    for (int kc = 0; kc < 8; ++kc) {
        const int c0 = kc * 64;
        __syncthreads();
        {
            int row = tid >> 1, co = (tid & 1) * 32;
            const int4* srca = (const int4*)(attn + ((long)(nt * 128 + row)) * C_ + c0 + co);
            int4* dsta = (int4*)&Aa[row][co];
            dsta[0] = srca[0]; dsta[1] = srca[1]; dsta[2] = srca[2]; dsta[3] = srca[3];
            int j = row;
            const int4* srcb = (const int4*)(Wpt + (long)(jt * 128 + j) * C_ + c0 + co);
            int4* dstb = (int4*)&Bw[j][co];
            dstb[0] = srcb[0]; dstb[1] = srcb[1]; dstb[2] = srcb[2]; dstb[3] = srcb[3];
        }
        __syncthreads();
        #pragma unroll
        for (int ks = 0; ks < 2; ++ks) {
            bf16x8 a[2], bb[8];
            #pragma unroll
            for (int mi = 0; mi < 2; mi++)
                a[mi] = *(const bf16x8*)&Aa[w * 32 + mi * 16 + lr][ks * 32 + lq * 8];
            #pragma unroll
            for (int ji = 0; ji < 8; ji++)
                bb[ji] = *(const bf16x8*)&Bw[ji * 16 + lr][ks * 32 + lq * 8];
            #pragma unroll
            for (int mi = 0; mi < 2; mi++)
                #pragma unroll
                for (int ji = 0; ji < 8; ji++)
                    acc[mi][ji] = __builtin_amdgcn_mfma_f32_16x16x32_bf16(
                        a[mi], bb[ji], acc[mi][ji], 0, 0, 0);
        }
    }
    #pragma unroll
    for (int half = 0; half < 2; ++half) {
        __syncthreads();
        #pragma unroll
        for (int mi = 0; mi < 2; mi++) {
            int nl = w * 32 + mi * 16 + lq * 4;
            #pragma unroll
            for (int ji = 0; ji < 4; ji++) {
                int cl = ji * 16 + lr;
                float bs = bproj[jt * 128 + half * 64 + cl];
                f32x4 v = acc[mi][half * 4 + ji];
                #pragma unroll
                for (int r = 0; r < 4; r++) v[r] += bs;
                *(f32x4*)&outT[cl][nl] = v;     // ds_write_b128
            }
        }
        __syncthreads();
        {
            int cl = tid >> 2, ch = (tid & 3) * 32;
            const float* sp = &outT[cl][ch];
            float* dp = out + ((long)(b * C_ + jt * 128 + half * 64 + cl)) * N_ + nloc + ch;
            #pragma unroll
            for (int k = 0; k < 8; ++k)
                ((float4*)dp)[k] = ((const float4*)sp)[k];
        }
    }
}

// ===========================================================================
// Round-1 fp32 fallback (used only if ws_size is too small for the MFMA path)
// ===========================================================================
__global__ __launch_bounds__(256) void kernelA_fb(
        const float* __restrict__ x, const float* __restrict__ Wqkv,
        const float* __restrict__ bqkv, float* __restrict__ S_g,
        float* __restrict__ ksum_g) {
    const int h = blockIdx.x;
    const int s = blockIdx.y;
    const int b = blockIdx.z;
    const int tid = threadIdx.x;
    const int tn = tid & 15;
    const int tj = tid >> 4;
    const int td = tid & 15;
    const int te = tid >> 4;

    __shared__ float As[16][64];
    __shared__ float Bs[16][128];
    __shared__ float kphi_s[64][64];
    __shared__ float v_s[64][64];

    float acc2[4][4];
    #pragma unroll
    for (int i = 0; i < 4; i++)
        #pragma unroll
        for (int j = 0; j < 4; j++) acc2[i][j] = 0.f;
    float ksum_r = 0.f;

    float bias_j[8];
    #pragma unroll
    for (int jj = 0; jj < 8; jj++) {
        int j = tj * 8 + jj;
        int col = (j < 64) ? (512 + h * 64 + j) : (1024 + h * 64 + (j - 64));
        bias_j[jj] = bqkv[col];
    }

    for (int it = 0; it < 8; ++it) {
        const int n0 = (s * 8 + it) * 64;
        float acc[4][8];
        #pragma unroll
        for (int i = 0; i < 4; i++)
            #pragma unroll
            for (int jj = 0; jj < 8; jj++) acc[i][jj] = 0.f;

        for (int kc = 0; kc < 32; ++kc) {
            const int c0 = kc * 16;
            __syncthreads();
            {
                int r = tid >> 4, n4 = (tid & 15) * 4;
                const float* src = x + ((size_t)b * C_ + (c0 + r)) * (size_t)N_ + n0 + n4;
                *(float4*)&As[r][n4] = *(const float4*)src;
            }
            #pragma unroll
            for (int part = 0; part < 2; ++part) {
                int idx = tid + part * 256;
                int r = idx >> 5;
                int j4 = (idx & 31) * 4;
                int col = (j4 < 64) ? (512 + h * 64 + j4) : (1024 + h * 64 + (j4 - 64));
                const float* src = Wqkv + (size_t)(c0 + r) * C3_ + col;
                *(float4*)&Bs[r][j4] = *(const float4*)src;
            }
            __syncthreads();
            #pragma unroll
            for (int k = 0; k < 16; ++k) {
                float a[4], bb[8];
                *(float4*)a      = *(const float4*)&As[k][tn * 4];
                *(float4*)&bb[0] = *(const float4*)&Bs[k][tj * 8];
                *(float4*)&bb[4] = *(const float4*)&Bs[k][tj * 8 + 4];
                #pragma unroll
                for (int i = 0; i < 4; i++)
                    #pragma unroll
                    for (int jj = 0; jj < 8; jj++)
                        acc[i][jj] = fmaf(a[i], bb[jj], acc[i][jj]);
            }
        }
        __syncthreads();
        if (tj < 8) {
            #pragma unroll
            for (int i = 0; i < 4; i++) {
                int n = tn * 4 + i;
                float tmp[8];
                #pragma unroll
                for (int jj = 0; jj < 8; jj++) tmp[jj] = phi_f(acc[i][jj] + bias_j[jj]);
                *(float4*)&kphi_s[n][tj * 8]     = *(float4*)&tmp[0];
                *(float4*)&kphi_s[n][tj * 8 + 4] = *(float4*)&tmp[4];
            }
        } else {
            #pragma unroll
            for (int i = 0; i < 4; i++) {
                int n = tn * 4 + i;
                float tmp[8];
                #pragma unroll
                for (int jj = 0; jj < 8; jj++) tmp[jj] = acc[i][jj] + bias_j[jj];
                *(float4*)&v_s[n][(tj - 8) * 8]     = *(float4*)&tmp[0];
                *(float4*)&v_s[n][(tj - 8) * 8 + 4] = *(float4*)&tmp[4];
            }
        }
        __syncthreads();
        #pragma unroll 4
        for (int n = 0; n < 64; ++n) {
            float a[4], bb[4];
            *(float4*)a  = *(const float4*)&kphi_s[n][td * 4];
            *(float4*)bb = *(const float4*)&v_s[n][te * 4];
            #pragma unroll
            for (int dd = 0; dd < 4; dd++)
                #pragma unroll
                for (int ee = 0; ee < 4; ee++)
                    acc2[dd][ee] = fmaf(a[dd], bb[ee], acc2[dd][ee]);
        }
        if (tid < 64) {
            float sum = 0.f;
            #pragma unroll 8
            for (int n = 0; n < 64; ++n) sum += kphi_s[n][tid];
            ksum_r += sum;
        }
    }

    const int bh = b * H_ + h;
    #pragma unroll
    for (int dd = 0; dd < 4; dd++)
        #pragma unroll
        for (int ee = 0; ee < 4; ee++)
            atomicAdd(&S_g[((size_t)bh * 64 + td * 4 + dd) * 64 + te * 4 + ee], acc2[dd][ee]);
    if (tid < 64) atomicAdd(&ksum_g[bh * 64 + tid], ksum_r);
}

__global__ __launch_bounds__(256) void kernelB_fb(
        const float* __restrict__ x, const float* __restrict__ Wqkv,
        const float* __restrict__ bqkv, const float* __restrict__ Wproj,
        const float* __restrict__ bproj, const float* __restrict__ S_g,
        const float* __restrict__ ksum_g, float* __restrict__ out) {
    const int nt = blockIdx.x;
    const int b  = blockIdx.y;
    const int n0 = nt * 16;
    const int tid = threadIdx.x;
    const int tn = tid & 3;
    const int tj = tid >> 2;

    __shared__ float QA[512][16];
    __shared__ float As[16][16];
    __shared__ float Bs2[16][256];
    __shared__ float SB[16][64];
    __shared__ float ksumL[512];
    __shared__ float denL[16];

    ksumL[tid]       = ksum_g[(size_t)b * 512 + tid];
    ksumL[tid + 256] = ksum_g[(size_t)b * 512 + tid + 256];

    for (int half = 0; half < 2; ++half) {
        float acc[4][4];
        #pragma unroll
        for (int i = 0; i < 4; i++)
            #pragma unroll
            for (int j = 0; j < 4; j++) acc[i][j] = 0.f;

        for (int kc = 0; kc < 32; ++kc) {
            const int c0 = kc * 16;
            __syncthreads();
            {
                int r = tid >> 4, n = tid & 15;
                As[r][n] = x[((size_t)b * C_ + c0 + r) * (size_t)N_ + n0 + n];
            }
            {
                int r = tid >> 4;
                int j0 = (tid & 15) * 16;
                const float* src = Wqkv + (size_t)(c0 + r) * C3_ + half * 256 + j0;
                float4* dst = (float4*)&Bs2[r][j0];
                #pragma unroll
                for (int q4 = 0; q4 < 4; q4++) dst[q4] = ((const float4*)src)[q4];
            }
            __syncthreads();
            #pragma unroll
            for (int k = 0; k < 16; ++k) {
                float a[4], bb[4];
                *(float4*)a  = *(const float4*)&As[k][tn * 4];
                *(float4*)bb = *(const float4*)&Bs2[k][tj * 4];
                #pragma unroll
                for (int i = 0; i < 4; i++)
                    #pragma unroll
                    for (int jj = 0; jj < 4; jj++)
                        acc[i][jj] = fmaf(a[i], bb[jj], acc[i][jj]);
            }
        }
        #pragma unroll
        for (int jj = 0; jj < 4; jj++) {
            int c = half * 256 + tj * 4 + jj;
            float bq = bqkv[c];
            float tmp[4];
            #pragma unroll
            for (int i = 0; i < 4; i++) tmp[i] = phi_f(acc[i][jj] + bq);
            *(float4*)&QA[c][tn * 4] = *(float4*)tmp;
        }
    }
    __syncthreads();

    for (int h = 0; h < H_; ++h) {
        if (tid < 16) {
            float d = 0.f;
            #pragma unroll 8
            for (int dd = 0; dd < 64; ++dd)
                d = fmaf(QA[h * 64 + dd][tid], ksumL[h * 64 + dd], d);
            denL[tid] = d + EPS;
        }
        float acc4[4] = {0.f, 0.f, 0.f, 0.f};
        for (int dc = 0; dc < 4; ++dc) {
            __syncthreads();
            {
                int r = tid >> 4, e4 = (tid & 15) * 4;
                *(float4*)&SB[r][e4] =
                    *(const float4*)&S_g[(((size_t)(b * H_ + h)) * 64 + dc * 16 + r) * 64 + e4];
            }
            __syncthreads();
            #pragma unroll
            for (int k = 0; k < 16; ++k) {
                float a[4];
                *(float4*)a = *(const float4*)&QA[h * 64 + dc * 16 + k][tn * 4];
                float bb = SB[k][tj];
                #pragma unroll
                for (int i = 0; i < 4; i++) acc4[i] = fmaf(a[i], bb, acc4[i]);
            }
        }
        __syncthreads();
        {
            float tmp[4];
            #pragma unroll
            for (int i = 0; i < 4; i++) tmp[i] = acc4[i] / denL[tn * 4 + i];
            *(float4*)&QA[h * 64 + tj][tn * 4] = *(float4*)tmp;
        }
        __syncthreads();
    }

    for (int half = 0; half < 2; ++half) {
        float acc[4][4];
        #pragma unroll
        for (int i = 0; i < 4; i++)
            #pragma unroll
            for (int j = 0; j < 4; j++) acc[i][j] = 0.f;

        for (int kc = 0; kc < 32; ++kc) {
            __syncthreads();
            {
                int r = tid >> 4;
                int j0 = (tid & 15) * 16;
                const float* src = Wproj + (size_t)(kc * 16 + r) * C_ + half * 256 + j0;
                float4* dst = (float4*)&Bs2[r][j0];
                #pragma unroll
                for (int q4 = 0; q4 < 4; q4++) dst[q4] = ((const float4*)src)[q4];
            }
            __syncthreads();
            #pragma unroll
            for (int k = 0; k < 16; ++k) {
                float a[4], bb[4];
                *(float4*)a  = *(const float4*)&QA[kc * 16 + k][tn * 4];
                *(float4*)bb = *(const float4*)&Bs2[k][tj * 4];
                #pragma unroll
                for (int i = 0; i < 4; i++)
                    #pragma unroll
                    for (int jj = 0; jj < 4; jj++)
                        acc[i][jj] = fmaf(a[i], bb[jj], acc[i][jj]);
            }
        }
        #pragma unroll
        for (int jj = 0; jj < 4; jj++) {
            int c = half * 256 + tj * 4 + jj;
            float bp = bproj[c];
            float tmp[4];
            #pragma unroll
            for (int i = 0; i < 4; i++) tmp[i] = acc[i][jj] + bp;
            *(float4*)&out[((size_t)b * C_ + c) * (size_t)N_ + n0 + tn * 4] = *(float4*)tmp;
        }
    }
}

// ===========================================================================
extern "C" void kernel_launch(void* const* d_in, const int* in_sizes, int n_in,
                              void* d_out, int out_size, void* d_ws, size_t ws_size,
                              hipStream_t stream) {
    const float* x     = (const float*)d_in[0];
    const float* Wqkv  = (const float*)d_in[1];
    const float* bqkv  = (const float*)d_in[2];
    const float* Wproj = (const float*)d_in[3];
    const float* bproj = (const float*)d_in[4];
    float* out = (float*)d_out;

    // ---- workspace layout (bytes) ----
    const size_t oS    = 0;                        // S_g f32 [32][64][64]   524288
    const size_t oK    = oS + 524288;              // ksum f32 [32][64]      8192
    const size_t oXT   = oK + 8192;                // xt bf16 [4][16384][512] 67108864
    const size_t oWq   = oXT + 67108864;           // Wq_t bf16 [1536][512]  1572864
    const size_t oWp   = oWq + 1572864;            // Wp_t bf16 [512][512]   524288
    const size_t oSbT  = oWp + 524288;             // SbT bf16 [32][160][64] 655360
    const size_t oAttn = oSbT + 655360;            // attn bf16 [4][16384][512] 67108864
    const size_t need  = oAttn + 67108864;         // = 137,502,720

    float* S_g    = (float*)((char*)d_ws + oS);
    float* ksum_g = (float*)((char*)d_ws + oK);

    if (ws_size < need) {
        // fp32 fallback (round-1 path)
        hipMemsetAsync(d_ws, 0, 532480, stream);
        kernelA_fb<<<dim3(H_, 32, B_), 256, 0, stream>>>(x, Wqkv, bqkv, S_g, ksum_g);
        kernelB_fb<<<dim3(N_ / 16, B_), 256, 0, stream>>>(x, Wqkv, bqkv, Wproj, bproj,
                                                          S_g, ksum_g, out);
        return;
    }

    ushort* xt   = (ushort*)((char*)d_ws + oXT);
    ushort* Wqt  = (ushort*)((char*)d_ws + oWq);
    ushort* Wpt  = (ushort*)((char*)d_ws + oWp);
    ushort* SbT  = (ushort*)((char*)d_ws + oSbT);
    ushort* attn = (ushort*)((char*)d_ws + oAttn);

    hipMemsetAsync(d_ws, 0, 532480, stream);  // S_g + ksum
    k_transpose<<<dim3(N_ / 64, C_ / 64, B_), 256, 0, stream>>>(
        x, xt, C_, N_, (long)C_ * N_, (long)N_ * C_);
    k_transpose<<<dim3(C3_ / 64, C_ / 64, 1), 256, 0, stream>>>(
        Wqkv, Wqt, C_, C3_, 0, 0);
    k_transpose<<<dim3(C_ / 64, C_ / 64, 1), 256, 0, stream>>>(
        Wproj, Wpt, C_, C_, 0, 0);
    k_kv_s<<<dim3(16, H_, B_), 256, 0, stream>>>(xt, Wqt, bqkv, S_g, ksum_g);
    k_sfin<<<dim3(B_ * H_), 256, 0, stream>>>(S_g, ksum_g, SbT);
    k_q_attn<<<dim3(N_ / 128, H_, B_), 256, 0, stream>>>(xt, Wqt, bqkv, SbT, attn);
    k_proj<<<dim3((B_ * N_) / 128, 4), 256, 0, stream>>>(attn, Wpt, bproj, out);
}